// Round 21
// baseline (189.903 us; speedup 1.0000x reference)
//
#include <hip/hip_runtime.h>
#include <math.h>

#define NN 4096
#define TT 32
#define FF 7
#define HH 64
#define NHEAD 8
#define DOUT 8
#define LOG2E 1.44269504f

#if __has_builtin(__builtin_amdgcn_exp2f)
#define EXP2(x) __builtin_amdgcn_exp2f(x)
#else
#define EXP2(x) exp2f(x)
#endif

typedef short bf16x8 __attribute__((ext_vector_type(8)));
typedef float f32x4 __attribute__((ext_vector_type(4)));

__device__ __forceinline__ float sigm(float x){
  x = fminf(fmaxf(x, -30.f), 30.f);
  return 1.f / (1.f + __expf(-x));
}
__device__ __forceinline__ float tanh_fast(float x){
  x = fminf(fmaxf(x, -15.f), 15.f);
  float e = __expf(2.f*x);
  return (e - 1.f) / (e + 1.f);
}
__device__ __forceinline__ unsigned short bf16rne(float f){
  unsigned u = __float_as_uint(f);
  u += 0x7fffu + ((u >> 16) & 1u);
  return (unsigned short)(u >> 16);
}
__device__ __forceinline__ unsigned bfpack2(float a, float b){
  return (unsigned)bf16rne(a) | ((unsigned)bf16rne(b) << 16);
}
__device__ __forceinline__ unsigned cvtpk_bf16(float a, float b){
  unsigned r;
  asm("v_cvt_pk_bf16_f32 %0, %1, %2" : "=v"(r) : "v"(a), "v"(b));
  return r;
}

// ---------------- K0: weight transposes (0-15) + GRU frag pack (16-24) + ones ----------------
__global__ __launch_bounds__(256) void k0_prep(
    const float* __restrict__ pw, const float* __restrict__ msw,
    const float* __restrict__ mpw, const float* __restrict__ sw1,
    const float* __restrict__ Wih, const float* __restrict__ Whh,
    const float* __restrict__ bih, const float* __restrict__ bhh,
    float* __restrict__ wtproj, float* __restrict__ wtself,
    float* __restrict__ wtpos, float* __restrict__ wtsem,
    uint4* __restrict__ whhF, uint4* __restrict__ wihF,
    unsigned* __restrict__ onesb)
{
  if (blockIdx.x < 16){
    int tid = threadIdx.x + blockIdx.x*256;
    int d = tid >> 6, k = tid & 63;
    wtproj[k*64+d] = pw[tid];
    wtself[k*64+d] = msw[tid];
    wtpos[k*64+d]  = mpw[tid];
    wtsem[k*64+d]  = sw1[tid];
    return;
  }
  if (blockIdx.x == 16 && threadIdx.x < 32) onesb[threadIdx.x] = 0x3f803f80u;
  int idx = (blockIdx.x-16)*256 + threadIdx.x;     // 0..2303
  if (idx < 24*64){
    int f = idx >> 6, lane = idx & 63;
    int T = f >> 1, c = f & 1;
    int g = T*16 + (lane & 15);
    const float* wp = Whh + g*64 + c*32 + (lane >> 4)*8;
    uint4 v;
    v.x = bfpack2(wp[0], wp[1]);
    v.y = bfpack2(wp[2], wp[3]);
    v.z = bfpack2(wp[4], wp[5]);
    v.w = bfpack2(wp[6], wp[7]);
    whhF[idx] = v;
  } else if (idx < 36*64){
    int i2 = idx - 24*64;
    int T = i2 >> 6, lane = i2 & 63;
    int g = T*16 + (lane & 15);
    int kg = lane >> 4;
    float bias = (T < 8) ? (bih[g] + bhh[g]) : bih[g];   // b_hhn NOT folded (inside r*())
    float f8[8];
    #pragma unroll
    for (int j = 0; j < 8; ++j){
      int k = kg*8 + j;
      f8[j] = (k < 7) ? Wih[g*7 + k] : ((k == 7) ? bias : 0.f);
    }
    uint4 v;
    v.x = bfpack2(f8[0], f8[1]); v.y = bfpack2(f8[2], f8[3]);
    v.z = bfpack2(f8[4], f8[5]); v.w = bfpack2(f8[6], f8[7]);
    wihF[i2] = v;
  }
}

// ---------------- K1 fused: single-wave GRU (blocks 0-255) + adj pack (256-1279) ----------------
// GRU: ONE wave per block holds all 36 A-fragments, asm-pinned into VGPRs
// (rounds 11-14 failed because the compiler rematerialized them from memory
// each t; "+v" asm makes them opaque/unrematerializable). Barrier-free t-loop
// (in-wave DS ordering) kills the per-t cross-SIMD __syncthreads that made the
// 4-wave split ~45us. Waves 1-3 stage x then exit. Pack blocks hide under it.
__global__ __launch_bounds__(256, 1) void k1_fused(
    const float* __restrict__ x,      // [N][T][F]
    const uint4* __restrict__ whhF,   // [24][64]
    const uint4* __restrict__ wihF,   // [12][64]
    const float* __restrict__ bhh,
    float* __restrict__ hout,         // [N][64]
    const int* __restrict__ adj,
    unsigned long long* __restrict__ adjmT)
{
  __shared__ __align__(16) short s_xb[32][16][8];   // 8KB   bf16 x (k=7 -> 1.0)
  __shared__ __align__(16) short s_hb[16][72];      // 2.25KB bf16 h (pad 72)

  int tid = threadIdx.x;
  int lane = tid & 63, w = tid >> 6;

  if (blockIdx.x >= 256){
    // ---- adjacency pack: row-major adj -> transposed 64-bit masks ----
    int row = (blockIdx.x - 256)*4 + w;
    const int* ap = adj + (size_t)row*NN;
    size_t base = (size_t)(row >> 4)*1024 + (row & 15);
    #pragma unroll 8
    for (int s = 0; s < 64; ++s){
      unsigned long long m = __ballot(ap[s*64 + lane] != 0);
      if (lane == 0) adjmT[base + s*16] = m;
    }
    return;
  }

  int nb = blockIdx.x * 16;

  // all 4 waves stage x + zero h, then waves 1-3 exit
  for (int s = tid; s < 4096; s += 256){
    int t = s >> 7, node = (s >> 3) & 15, k = s & 7;
    float v = (k < 7) ? x[(size_t)(nb + node)*224 + t*7 + k] : ((k == 7) ? 1.f : 0.f);
    s_xb[t][node][k] = (short)bf16rne(v);
  }
  for (int i = tid; i < 576; i += 256) ((unsigned*)&s_hb[0][0])[i] = 0u;
  __syncthreads();
  if (w != 0) return;

  int row = lane & 15;          // A: gate row within tile / B,D: node column
  int kg  = lane >> 4;          // k-group (8 elements each)

  union U { bf16x8 v; uint4 q; };
  bf16x8 whh_f[24];
  #pragma unroll
  for (int i = 0; i < 24; ++i){ U u; u.q = whhF[i*64 + lane]; whh_f[i] = u.v; }
  bf16x8 wih_f[12];
  #pragma unroll
  for (int i = 0; i < 12; ++i){ U u; u.q = wihF[i*64 + lane]; wih_f[i] = u.v; }
  // pin: opaque values cannot be rematerialized -> stay VGPR-resident
  #pragma unroll
  for (int i = 0; i < 24; ++i) asm volatile("" : "+v"(whh_f[i]));
  #pragma unroll
  for (int i = 0; i < 12; ++i) asm volatile("" : "+v"(wih_f[i]));

  float bhn_[4][4];
  #pragma unroll
  for (int T = 0; T < 4; ++T)
    #pragma unroll
    for (int j = 0; j < 4; ++j)
      bhn_[T][j] = bhh[128 + T*16 + kg*4 + j];

  float hreg[4][4];
  #pragma unroll
  for (int T = 0; T < 4; ++T)
    #pragma unroll
    for (int j = 0; j < 4; ++j) hreg[T][j] = 0.f;

  f32x4 z4 = {0.f, 0.f, 0.f, 0.f};

  for (int t = 0; t < TT; ++t){
    bf16x8 bx = {0,0,0,0,0,0,0,0};
    if (lane < 16) bx = *(const bf16x8*)&s_xb[t][row][0];
    bf16x8 bh0 = *(const bf16x8*)&s_hb[row][kg*8];
    bf16x8 bh1 = *(const bf16x8*)&s_hb[row][32 + kg*8];

    #pragma unroll
    for (int Tr = 0; Tr < 4; ++Tr){
      f32x4 aR = __builtin_amdgcn_mfma_f32_16x16x32_bf16(wih_f[Tr], bx, z4, 0, 0, 0);
      aR = __builtin_amdgcn_mfma_f32_16x16x32_bf16(whh_f[Tr*2+0], bh0, aR, 0, 0, 0);
      aR = __builtin_amdgcn_mfma_f32_16x16x32_bf16(whh_f[Tr*2+1], bh1, aR, 0, 0, 0);
      f32x4 aZ = __builtin_amdgcn_mfma_f32_16x16x32_bf16(wih_f[4+Tr], bx, z4, 0, 0, 0);
      aZ = __builtin_amdgcn_mfma_f32_16x16x32_bf16(whh_f[(4+Tr)*2+0], bh0, aZ, 0, 0, 0);
      aZ = __builtin_amdgcn_mfma_f32_16x16x32_bf16(whh_f[(4+Tr)*2+1], bh1, aZ, 0, 0, 0);
      f32x4 aNx = __builtin_amdgcn_mfma_f32_16x16x32_bf16(wih_f[8+Tr], bx, z4, 0, 0, 0);
      f32x4 aNh = __builtin_amdgcn_mfma_f32_16x16x32_bf16(whh_f[(8+Tr)*2+0], bh0, z4, 0, 0, 0);
      aNh = __builtin_amdgcn_mfma_f32_16x16x32_bf16(whh_f[(8+Tr)*2+1], bh1, aNh, 0, 0, 0);
      #pragma unroll
      for (int j = 0; j < 4; ++j){
        float rr = sigm(aR[j]);
        float zz = sigm(aZ[j]);
        float nn = tanh_fast(aNx[j] + rr*(aNh[j] + bhn_[Tr][j]));
        hreg[Tr][j] = (1.f - zz)*nn + zz*hreg[Tr][j];
      }
    }
    // repack h -> bf16 B-layout for next t (in-wave DS ordering: no barrier)
    #pragma unroll
    for (int Tr = 0; Tr < 4; ++Tr){
      uint2 p;
      p.x = bfpack2(hreg[Tr][0], hreg[Tr][1]);
      p.y = bfpack2(hreg[Tr][2], hreg[Tr][3]);
      *(uint2*)&s_hb[row][Tr*16 + kg*4] = p;
    }
  }

  #pragma unroll
  for (int Tr = 0; Tr < 4; ++Tr)
    #pragma unroll
    for (int j = 0; j < 4; ++j)
      hout[(size_t)(nb + row)*64 + Tr*16 + kg*4 + j] = hreg[Tr][j];
}

// ---------------- K2: supbJ (bf16, j-blocked) = h@gat_w; f1t/f2 pre-scaled by log2e ----------------
__global__ __launch_bounds__(256) void k2_sup(
    const float* __restrict__ h, const float* __restrict__ gat_w,
    const float* __restrict__ wu, const float* __restrict__ wv,
    unsigned short* __restrict__ supbJ, // [8][512][8][8] bf16
    float* __restrict__ f1t,            // [8][N]  (x log2e)
    float* __restrict__ f2)             // [N][8]  (x log2e)
{
  int tid = threadIdx.x;
  int wave = tid >> 6, lane = tid & 63;
  int n = blockIdx.x*4 + wave;
  float hreg = h[n*64 + lane];
  float acc = 0.f;
  #pragma unroll
  for (int k = 0; k < 64; ++k){
    float hk = __shfl(hreg, k, 64);
    acc += hk * gat_w[k*64 + lane];
  }
  int hh = lane >> 3, o = lane & 7;
  supbJ[(size_t)hh*32768 + (n>>3)*64 + o*8 + (n&7)] = bf16rne(acc);
  float p1 = acc * wu[lane];
  float p2 = acc * wv[lane];
  #pragma unroll
  for (int s = 1; s < 8; s <<= 1){
    p1 += __shfl_xor(p1, s, 64);
    p2 += __shfl_xor(p2, s, 64);
  }
  if (o == 0){
    f1t[(size_t)hh*NN + n] = p1 * LOG2E;   // exp(x) == exp2(x*log2e)
    f2[n*8 + hh] = p2 * LOG2E;
  }
}

// ---------------- K3: flash-style MFMA GAT, 4-way j-split, coalesced loads ----------------
// Round-17 exp form + pointer-base B select (col>=8 lanes read a 16B ones
// buffer; boff = X & bmask -> 1 v_and replaces 4 cndmask + select per chunk).
__global__ __launch_bounds__(256) void k3_gat(
    const unsigned long long* __restrict__ adjmT,  // [256][64][16]
    const unsigned short* __restrict__ supbJ,      // [8][512][8][8] bf16
    const float* __restrict__ f1t,                 // [8][N]  (x log2e)
    const float* __restrict__ f2,                  // [N][8]  (x log2e)
    const unsigned short* __restrict__ onesb,      // 64 bf16 1.0
    float* __restrict__ posg)
{
  __shared__ f32x4 s_acc[4][64];        // 4KB merge buffer
  int tid = threadIdx.x;
  int lane = tid & 63, js = tid >> 6;
  int gid = blockIdx.x;                 // 0..2047
  int ib = gid >> 3, h = gid & 7;
  int i0 = ib*16;
  int col = lane & 15;
  int kg  = lane >> 4;

  float f2v = f2[(size_t)(i0+col)*8 + h];   // already x log2e

  const unsigned long long* mrowT = adjmT + (size_t)ib*1024;
  const float* f1p = f1t + (size_t)h*NN;
  int bmask = (col >= 8) ? 0 : -1;
  const unsigned short* bbase = (col >= 8) ? onesb
                                           : (supbJ + (size_t)h*32768 + (col & 7)*8);

  f32x4 acc = {0.f, 0.f, 0.f, 0.f};

  #pragma unroll 4
  for (int cc = 0; cc < 32; ++cc){
    int c = js*32 + cc;
    int j8 = c*32 + kg*8;
    unsigned long long mw = mrowT[(c >> 1)*16 + col];          // 128B contiguous
    unsigned mb = (unsigned)(mw >> (((c & 1) << 5) + (kg << 3)));
    float4 fa = *(const float4*)(f1p + j8);
    float4 fb = *(const float4*)(f1p + j8 + 4);

    float p[8];
    p[0]=fa.x; p[1]=fa.y; p[2]=fa.z; p[3]=fa.w;
    p[4]=fb.x; p[5]=fb.y; p[6]=fb.z; p[7]=fb.w;
    #pragma unroll
    for (int e = 0; e < 8; ++e){
      float ls = p[e] + f2v;                 // (f1+f2)*log2e
      float lrs = fmaxf(ls, 0.2f*ls);        // leaky-relu commutes with +scale
      float pe = EXP2(lrs);                  // raw v_exp_f32
      p[e] = (mb & (1u << e)) ? pe : 0.f;
    }
    union { bf16x8 v; unsigned u[4]; } A;
    A.u[0] = cvtpk_bf16(p[0], p[1]);
    A.u[1] = cvtpk_bf16(p[2], p[3]);
    A.u[2] = cvtpk_bf16(p[4], p[5]);
    A.u[3] = cvtpk_bf16(p[6], p[7]);

    int boff = ((c*4 + kg) << 6) & bmask;
    union { bf16x8 v; uint4 q; } B;
    B.q = *(const uint4*)(bbase + boff);      // contiguous 512B/wave (or ones)

    acc = __builtin_amdgcn_mfma_f32_16x16x32_bf16(A.v, B.v, acc, 0, 0, 0);
  }

  s_acc[js][lane] = acc;
  __syncthreads();
  if (js == 0){
    f32x4 a1 = s_acc[1][lane], a2 = s_acc[2][lane], a3 = s_acc[3][lane];
    #pragma unroll
    for (int j = 0; j < 4; ++j) acc[j] += a1[j] + a2[j] + a3[j];

    int slane = (lane & 48) + 8;
    #pragma unroll
    for (int r4 = 0; r4 < 4; ++r4){
      float sv = __shfl(acc[r4], slane, 64);
      float inv = 1.f / fmaxf(sv, 1e-10f);
      if (col < 8)
        posg[(size_t)(i0 + kg*4 + r4)*64 + h*8 + col] = acc[r4] * inv;
    }
  }
}

// ---------------- K4: residual proj + the two MLP channels + PairNorm partials ----------------
__global__ __launch_bounds__(256) void k4_mix(
    const float* __restrict__ h, const float* __restrict__ posg,
    const float* __restrict__ gat_bias, const float* __restrict__ proj_b,
    const float* __restrict__ wtproj, const float* __restrict__ wtself,
    const float* __restrict__ wtpos,
    const float* __restrict__ mlp_self_b, const float* __restrict__ mlp_pos_b,
    float* __restrict__ s0, float* __restrict__ s1, float* __restrict__ part)
{
  int tid = threadIdx.x;
  int wave = tid >> 6, lane = tid & 63;
  int n = blockIdx.x*4 + wave;
  float hreg = h[n*64 + lane];
  float pr = proj_b[lane];
  float se = mlp_self_b[lane];
  #pragma unroll
  for (int k = 0; k < 64; ++k){
    float hk = __shfl(hreg, k, 64);
    pr += hk * wtproj[k*64 + lane];
    se += hk * wtself[k*64 + lane];
  }
  float posf = posg[n*64 + lane] + gat_bias[lane] + pr;
  float s1v = mlp_pos_b[lane];
  #pragma unroll
  for (int k = 0; k < 64; ++k){
    float pk = __shfl(posf, k, 64);
    s1v += pk * wtpos[k*64 + lane];
  }
  s0[n*64+lane] = se;
  s1[n*64+lane] = s1v;

  __shared__ float sb0[4][64];
  __shared__ float sb1[4][64];
  __shared__ float sq[4];
  sb0[wave][lane] = se;
  sb1[wave][lane] = s1v;
  float q = se*se + s1v*s1v;
  #pragma unroll
  for (int s = 1; s < 64; s <<= 1) q += __shfl_xor(q, s, 64);
  if (lane == 0) sq[wave] = q;
  __syncthreads();
  if (tid < 64){
    part[blockIdx.x*130 + tid] = sb0[0][tid]+sb0[1][tid]+sb0[2][tid]+sb0[3][tid];
  } else if (tid < 128){
    int d = tid - 64;
    part[blockIdx.x*130 + 64 + d] = sb1[0][d]+sb1[1][d]+sb1[2][d]+sb1[3][d];
  } else if (tid == 128){
    part[blockIdx.x*130 + 128] = sq[0]+sq[1]+sq[2]+sq[3];
  }
}

// ---------------- K5: PairNorm stats (1024-thread two-stage reduce) ----------------
__global__ __launch_bounds__(1024) void k5_stats(const float* __restrict__ part, float* __restrict__ stats)
{
  int tid = threadIdx.x;
  __shared__ float s_mu[8][128];
  __shared__ float s_sq[8];
  int c = tid & 127, ch = tid >> 7;
  float a = 0.f;
  for (int b = ch*128; b < ch*128+128; ++b) a += part[b*130 + c];
  s_mu[ch][c] = a;
  if (tid < 8){
    float q = 0.f;
    for (int b = tid*128; b < tid*128+128; ++b) q += part[b*130 + 128];
    s_sq[tid] = q;
  }
  __syncthreads();
  if (tid < 128){
    float m = 0.f;
    #pragma unroll
    for (int j = 0; j < 8; ++j) m += s_mu[j][tid];
    s_mu[0][tid] = m;
    stats[tid] = m / 4096.f;
  }
  __syncthreads();
  if (tid == 0){
    float sq = 0.f;
    #pragma unroll
    for (int j = 0; j < 8; ++j) sq += s_sq[j];
    float mu2 = 0.f;
    for (int i = 0; i < 128; ++i){ float m = s_mu[0][i] / 4096.f; mu2 += m*m; }
    float msq = sq/(4096.f*64.f) - mu2/64.f;
    stats[128] = 1.f / sqrtf(1e-6f + msq);
  }
}

// ---------------- K6: semantic attention + predictor ----------------
__global__ __launch_bounds__(256) void k6_sem(
    const float* __restrict__ s0, const float* __restrict__ s1,
    const float* __restrict__ stats, const float* __restrict__ wtsem,
    const float* __restrict__ sem_b1, const float* __restrict__ sem_w2,
    const float* __restrict__ pred_w, const float* __restrict__ pred_b,
    float* __restrict__ out)
{
  int tid = threadIdx.x;
  int wave = tid >> 6, lane = tid & 63;
  int n = blockIdx.x*4 + wave;
  float rinv = stats[128];
  float a0 = (s0[n*64+lane] - stats[lane]) * rinv;
  float a1 = (s1[n*64+lane] - stats[64+lane]) * rinv;
  float t0 = sem_b1[lane], t1 = t0;
  #pragma unroll
  for (int k = 0; k < 64; ++k){
    float w = wtsem[k*64 + lane];
    t0 += __shfl(a0, k, 64) * w;
    t1 += __shfl(a1, k, 64) * w;
  }
  t0 = tanh_fast(t0); t1 = tanh_fast(t1);
  float w2 = sem_w2[lane];
  float w0 = t0*w2, w1 = t1*w2;
  #pragma unroll
  for (int s = 1; s < 64; s <<= 1){
    w0 += __shfl_xor(w0, s, 64);
    w1 += __shfl_xor(w1, s, 64);
  }
  float mx = fmaxf(w0, w1);
  float e0 = __expf(w0 - mx), e1 = __expf(w1 - mx);
  float denom = e0 + e1 + 1e-10f;
  float b0 = e0/denom, b1 = e1/denom;
  float emb = b0*a0 + b1*a1;
  float pl = emb * pred_w[lane];
  #pragma unroll
  for (int s = 1; s < 64; s <<= 1) pl += __shfl_xor(pl, s, 64);
  if (lane == 0) out[n] = sigm(pl + pred_b[0]);
}

extern "C" void kernel_launch(void* const* d_in, const int* in_sizes, int n_in,
                              void* d_out, int out_size, void* d_ws, size_t ws_size,
                              hipStream_t stream)
{
  (void)in_sizes; (void)n_in; (void)out_size; (void)ws_size;
  const float* x         = (const float*)d_in[0];
  const int*   adj       = (const int*)d_in[1];
  const float* W_ih      = (const float*)d_in[2];
  const float* W_hh      = (const float*)d_in[3];
  const float* b_ih      = (const float*)d_in[4];
  const float* b_hh      = (const float*)d_in[5];
  const float* gat_w     = (const float*)d_in[6];
  const float* gat_wu    = (const float*)d_in[7];
  const float* gat_wv    = (const float*)d_in[8];
  const float* gat_bias  = (const float*)d_in[9];
  const float* proj_w    = (const float*)d_in[10];
  const float* proj_b    = (const float*)d_in[11];
  const float* mlp_self_w= (const float*)d_in[12];
  const float* mlp_self_b= (const float*)d_in[13];
  const float* mlp_pos_w = (const float*)d_in[14];
  const float* mlp_pos_b = (const float*)d_in[15];
  const float* sem_w1    = (const float*)d_in[16];
  const float* sem_b1    = (const float*)d_in[17];
  const float* sem_w2    = (const float*)d_in[18];
  const float* pred_w    = (const float*)d_in[19];
  const float* pred_b    = (const float*)d_in[20];
  float* out = (float*)d_out;
  float* ws  = (float*)d_ws;

  float* h     = ws + 0;         // 0..262144
  unsigned short* supbJ = (unsigned short*)(ws + 262144);   // 512KB -> 393216
  float* f1t   = ws + 393216;    // 32768 -> 425984
  float* f2    = ws + 425984;    // 32768 -> 458752
  uint4* whhF  = (uint4*)(ws + 458752);   // 1536 uint4 -> 464896
  uint4* wihF  = (uint4*)(ws + 464896);   // 768 uint4 -> 467968
  unsigned* onesb = (unsigned*)(ws + 475136);               // 128B
  float* posg  = ws + 589824;    // 262144 -> 851968
  float* s0    = ws + 851968;    // 262144
  float* s1    = ws + 1114112;   // 262144
  // adjmT overlays s0+s1 (2MB, 851968..1376256): written by k1_fused pack-blocks,
  // consumed by k3, dead before k4 writes s0/s1. whhF/wihF/onesb OUTSIDE this range.
  unsigned long long* adjmT = (unsigned long long*)(ws + 851968);
  float* part  = ws + 1376256;   // 1024*130
  float* stats = ws + 1517576;   // 129
  float* wtproj= ws + 1517712;   // 4096
  float* wtself= wtproj + 4096;
  float* wtpos = wtself + 4096;
  float* wtsem = wtpos  + 4096;

  k0_prep<<<25, 256, 0, stream>>>(proj_w, mlp_self_w, mlp_pos_w, sem_w1,
                                  W_ih, W_hh, b_ih, b_hh,
                                  wtproj, wtself, wtpos, wtsem, whhF, wihF, onesb);
  k1_fused<<<1280, 256, 0, stream>>>(x, whhF, wihF, b_hh, h, adj, adjmT);
  k2_sup<<<1024, 256, 0, stream>>>(h, gat_w, gat_wu, gat_wv, supbJ, f1t, f2);
  k3_gat<<<2048, 256, 0, stream>>>(adjmT, supbJ, f1t, f2, (const unsigned short*)onesb, posg);
  k4_mix<<<1024, 256, 0, stream>>>(h, posg, gat_bias, proj_b, wtproj, wtself, wtpos,
                                   mlp_self_b, mlp_pos_b, s0, s1, part);
  k5_stats<<<1, 1024, 0, stream>>>(part, stats);
  k6_sem<<<1024, 256, 0, stream>>>(s0, s1, stats, wtsem, sem_b1, sem_w2, pred_w, pred_b, out);
}

// Round 22
// 147.961 us; speedup vs baseline: 1.2835x; 1.2835x over previous
//
#include <hip/hip_runtime.h>
#include <math.h>

#define NN 4096
#define TT 32
#define FF 7
#define HH 64
#define NHEAD 8
#define DOUT 8
#define LOG2E 1.44269504f

#if __has_builtin(__builtin_amdgcn_exp2f)
#define EXP2(x) __builtin_amdgcn_exp2f(x)
#else
#define EXP2(x) exp2f(x)
#endif

typedef short bf16x8 __attribute__((ext_vector_type(8)));
typedef float f32x4 __attribute__((ext_vector_type(4)));

__device__ __forceinline__ float sigm(float x){
  x = fminf(fmaxf(x, -30.f), 30.f);
  return 1.f / (1.f + __expf(-x));
}
__device__ __forceinline__ float tanh_fast(float x){
  x = fminf(fmaxf(x, -15.f), 15.f);
  float e = __expf(2.f*x);
  return (e - 1.f) / (e + 1.f);
}
__device__ __forceinline__ unsigned short bf16rne(float f){
  unsigned u = __float_as_uint(f);
  u += 0x7fffu + ((u >> 16) & 1u);
  return (unsigned short)(u >> 16);
}
__device__ __forceinline__ unsigned bfpack2(float a, float b){
  return (unsigned)bf16rne(a) | ((unsigned)bf16rne(b) << 16);
}
__device__ __forceinline__ unsigned cvtpk_bf16(float a, float b){
  unsigned r;
  asm("v_cvt_pk_bf16_f32 %0, %1, %2" : "=v"(r) : "v"(a), "v"(b));
  return r;
}

// ---------------- K0: weight transposes (0-15) + GRU frag pack (16-24) ----------------
__global__ __launch_bounds__(256) void k0_prep(
    const float* __restrict__ pw, const float* __restrict__ msw,
    const float* __restrict__ mpw, const float* __restrict__ sw1,
    const float* __restrict__ Wih, const float* __restrict__ Whh,
    const float* __restrict__ bih, const float* __restrict__ bhh,
    float* __restrict__ wtproj, float* __restrict__ wtself,
    float* __restrict__ wtpos, float* __restrict__ wtsem,
    uint4* __restrict__ whhF, uint4* __restrict__ wihF)
{
  if (blockIdx.x < 16){
    int tid = threadIdx.x + blockIdx.x*256;
    int d = tid >> 6, k = tid & 63;
    wtproj[k*64+d] = pw[tid];
    wtself[k*64+d] = msw[tid];
    wtpos[k*64+d]  = mpw[tid];
    wtsem[k*64+d]  = sw1[tid];
    return;
  }
  int idx = (blockIdx.x-16)*256 + threadIdx.x;     // 0..2303
  if (idx < 24*64){
    int f = idx >> 6, lane = idx & 63;
    int T = f >> 1, c = f & 1;
    int g = T*16 + (lane & 15);
    const float* wp = Whh + g*64 + c*32 + (lane >> 4)*8;
    uint4 v;
    v.x = bfpack2(wp[0], wp[1]);
    v.y = bfpack2(wp[2], wp[3]);
    v.z = bfpack2(wp[4], wp[5]);
    v.w = bfpack2(wp[6], wp[7]);
    whhF[idx] = v;
  } else if (idx < 36*64){
    int i2 = idx - 24*64;
    int T = i2 >> 6, lane = i2 & 63;
    int g = T*16 + (lane & 15);
    int kg = lane >> 4;
    float bias = (T < 8) ? (bih[g] + bhh[g]) : bih[g];   // b_hhn NOT folded (inside r*())
    float f8[8];
    #pragma unroll
    for (int j = 0; j < 8; ++j){
      int k = kg*8 + j;
      f8[j] = (k < 7) ? Wih[g*7 + k] : ((k == 7) ? bias : 0.f);
    }
    uint4 v;
    v.x = bfpack2(f8[0], f8[1]); v.y = bfpack2(f8[2], f8[3]);
    v.z = bfpack2(f8[4], f8[5]); v.w = bfpack2(f8[6], f8[7]);
    wihF[i2] = v;
  }
}

// ---------------- K1 fused: GRU (blocks 0-255) + adj bitmask pack (256-1279) ----------------
// GRU runs 1 block/CU (latency-bound, idle issue slots); the HBM-bound adj pack
// blocks co-reside and hide under it. 4-wave gate-split with per-t barrier:
// round-21 proved (3rd attempt) the compiler will NOT hold 36 fragments resident
// for a single-wave barrier-free version (VGPR stuck at 120, remat each t).
__global__ __launch_bounds__(256) void k1_fused(
    const float* __restrict__ x,      // [N][T][F]
    const uint4* __restrict__ whhF,   // [24][64]
    const uint4* __restrict__ wihF,   // [12][64]
    const float* __restrict__ bhh,
    float* __restrict__ hout,         // [N][64]
    const int* __restrict__ adj,
    unsigned long long* __restrict__ adjmT)
{
  __shared__ __align__(16) short s_xb[32][16][8];   // 8KB   bf16 x (k=7 -> 1.0)
  __shared__ __align__(16) short s_hb[2][16][72];   // 4.5KB bf16 h, double-buffered

  int tid = threadIdx.x;
  int lane = tid & 63, w = tid >> 6;

  if (blockIdx.x >= 256){
    // ---- adjacency pack: row-major adj -> transposed 64-bit masks ----
    int row = (blockIdx.x - 256)*4 + w;
    const int* ap = adj + (size_t)row*NN;
    size_t base = (size_t)(row >> 4)*1024 + (row & 15);
    #pragma unroll 8
    for (int s = 0; s < 64; ++s){
      unsigned long long m = __ballot(ap[s*64 + lane] != 0);
      if (lane == 0) adjmT[base + s*16] = m;
    }
    return;
  }

  // ---- GRU: block owns 16 nodes; wave w owns gate-tiles {w, 4+w, 8+w} ----
  int nb = blockIdx.x * 16;
  int row = lane & 15;
  int kg  = lane >> 4;

  union U { bf16x8 v; uint4 q; };
  U u;
  u.q = wihF[w*64 + lane];           bf16x8 fRx  = u.v;
  u.q = whhF[(w*2+0)*64 + lane];     bf16x8 fRh0 = u.v;
  u.q = whhF[(w*2+1)*64 + lane];     bf16x8 fRh1 = u.v;
  u.q = wihF[(4+w)*64 + lane];       bf16x8 fZx  = u.v;
  u.q = whhF[((4+w)*2+0)*64 + lane]; bf16x8 fZh0 = u.v;
  u.q = whhF[((4+w)*2+1)*64 + lane]; bf16x8 fZh1 = u.v;
  u.q = wihF[(8+w)*64 + lane];       bf16x8 fNx  = u.v;
  u.q = whhF[((8+w)*2+0)*64 + lane]; bf16x8 fNh0 = u.v;
  u.q = whhF[((8+w)*2+1)*64 + lane]; bf16x8 fNh1 = u.v;

  for (int s = tid; s < 4096; s += 256){
    int t = s >> 7, node = (s >> 3) & 15, k = s & 7;
    float v = (k < 7) ? x[(size_t)(nb + node)*224 + t*7 + k] : ((k == 7) ? 1.f : 0.f);
    s_xb[t][node][k] = (short)bf16rne(v);
  }
  for (int i = tid; i < 576; i += 256) ((unsigned*)&s_hb[0][0][0])[i] = 0u;

  float bhn_[4];
  #pragma unroll
  for (int j = 0; j < 4; ++j) bhn_[j] = bhh[128 + w*16 + kg*4 + j];
  float hreg[4] = {0.f, 0.f, 0.f, 0.f};
  f32x4 z4 = {0.f, 0.f, 0.f, 0.f};

  __syncthreads();
  int cur = 0;
  for (int t = 0; t < TT; ++t){
    bf16x8 bx = {0,0,0,0,0,0,0,0};
    if (lane < 16) bx = *(const bf16x8*)&s_xb[t][row][0];
    bf16x8 bh0 = *(const bf16x8*)&s_hb[cur][row][kg*8];
    bf16x8 bh1 = *(const bf16x8*)&s_hb[cur][row][32 + kg*8];

    f32x4 aR = __builtin_amdgcn_mfma_f32_16x16x32_bf16(fRx, bx, z4, 0, 0, 0);
    aR = __builtin_amdgcn_mfma_f32_16x16x32_bf16(fRh0, bh0, aR, 0, 0, 0);
    aR = __builtin_amdgcn_mfma_f32_16x16x32_bf16(fRh1, bh1, aR, 0, 0, 0);
    f32x4 aZ = __builtin_amdgcn_mfma_f32_16x16x32_bf16(fZx, bx, z4, 0, 0, 0);
    aZ = __builtin_amdgcn_mfma_f32_16x16x32_bf16(fZh0, bh0, aZ, 0, 0, 0);
    aZ = __builtin_amdgcn_mfma_f32_16x16x32_bf16(fZh1, bh1, aZ, 0, 0, 0);
    f32x4 aNx = __builtin_amdgcn_mfma_f32_16x16x32_bf16(fNx, bx, z4, 0, 0, 0);
    f32x4 aNh = __builtin_amdgcn_mfma_f32_16x16x32_bf16(fNh0, bh0, z4, 0, 0, 0);
    aNh = __builtin_amdgcn_mfma_f32_16x16x32_bf16(fNh1, bh1, aNh, 0, 0, 0);

    #pragma unroll
    for (int j = 0; j < 4; ++j){
      float rr = sigm(aR[j]);
      float zz = sigm(aZ[j]);
      float nn = tanh_fast(aNx[j] + rr*(aNh[j] + bhn_[j]));
      hreg[j] = (1.f - zz)*nn + zz*hreg[j];
    }
    uint2 p;
    p.x = bfpack2(hreg[0], hreg[1]);
    p.y = bfpack2(hreg[2], hreg[3]);
    *(uint2*)&s_hb[cur^1][row][w*16 + kg*4] = p;
    __syncthreads();
    cur ^= 1;
  }

  #pragma unroll
  for (int j = 0; j < 4; ++j)
    hout[(size_t)(nb + row)*64 + w*16 + kg*4 + j] = hreg[j];
}

// ---------------- K2: supbJ (bf16, j-blocked) = h@gat_w; f1t/f2 pre-scaled by log2e ----------------
__global__ __launch_bounds__(256) void k2_sup(
    const float* __restrict__ h, const float* __restrict__ gat_w,
    const float* __restrict__ wu, const float* __restrict__ wv,
    unsigned short* __restrict__ supbJ, // [8][512][8][8] bf16
    float* __restrict__ f1t,            // [8][N]  (x log2e)
    float* __restrict__ f2)             // [N][8]  (x log2e)
{
  int tid = threadIdx.x;
  int wave = tid >> 6, lane = tid & 63;
  int n = blockIdx.x*4 + wave;
  float hreg = h[n*64 + lane];
  float acc = 0.f;
  #pragma unroll
  for (int k = 0; k < 64; ++k){
    float hk = __shfl(hreg, k, 64);
    acc += hk * gat_w[k*64 + lane];
  }
  int hh = lane >> 3, o = lane & 7;
  supbJ[(size_t)hh*32768 + (n>>3)*64 + o*8 + (n&7)] = bf16rne(acc);
  float p1 = acc * wu[lane];
  float p2 = acc * wv[lane];
  #pragma unroll
  for (int s = 1; s < 8; s <<= 1){
    p1 += __shfl_xor(p1, s, 64);
    p2 += __shfl_xor(p2, s, 64);
  }
  if (o == 0){
    f1t[(size_t)hh*NN + n] = p1 * LOG2E;   // exp(x) == exp2(x*log2e)
    f2[n*8 + hh] = p2 * LOG2E;
  }
}

// ---------------- K3: flash-style MFMA GAT, 4-way j-split, coalesced loads ----------------
__global__ __launch_bounds__(256) void k3_gat(
    const unsigned long long* __restrict__ adjmT,  // [256][64][16]
    const unsigned short* __restrict__ supbJ,      // [8][512][8][8] bf16
    const float* __restrict__ f1t,                 // [8][N]  (x log2e)
    const float* __restrict__ f2,                  // [N][8]  (x log2e)
    float* __restrict__ posg)
{
  __shared__ f32x4 s_acc[4][64];        // 4KB merge buffer
  int tid = threadIdx.x;
  int lane = tid & 63, js = tid >> 6;
  int gid = blockIdx.x;                 // 0..2047
  int ib = gid >> 3, h = gid & 7;
  int i0 = ib*16;
  int col = lane & 15;
  int kg  = lane >> 4;

  float f2v = f2[(size_t)(i0+col)*8 + h];   // already x log2e

  const unsigned long long* mrowT = adjmT + (size_t)ib*1024;
  const float* f1p = f1t + (size_t)h*NN;
  const unsigned short* bsrcJ = supbJ + (size_t)h*32768;
  unsigned bge8 = (col >= 8) ? 0xffffffffu : 0u;

  f32x4 acc = {0.f, 0.f, 0.f, 0.f};

  #pragma unroll 4
  for (int cc = 0; cc < 32; ++cc){
    int c = js*32 + cc;
    int j8 = c*32 + kg*8;
    unsigned long long mw = mrowT[(c >> 1)*16 + col];          // 128B contiguous
    unsigned mb = (unsigned)(mw >> (((c & 1) << 5) + (kg << 3)));
    float4 fa = *(const float4*)(f1p + j8);
    float4 fb = *(const float4*)(f1p + j8 + 4);

    float p[8];
    p[0]=fa.x; p[1]=fa.y; p[2]=fa.z; p[3]=fa.w;
    p[4]=fb.x; p[5]=fb.y; p[6]=fb.z; p[7]=fb.w;
    #pragma unroll
    for (int e = 0; e < 8; ++e){
      float ls = p[e] + f2v;                 // (f1+f2)*log2e
      float lrs = fmaxf(ls, 0.2f*ls);        // leaky-relu commutes with +scale
      float pe = EXP2(lrs);                  // raw v_exp_f32
      p[e] = (mb & (1u << e)) ? pe : 0.f;
    }
    union { bf16x8 v; unsigned u[4]; } A;
    A.u[0] = cvtpk_bf16(p[0], p[1]);
    A.u[1] = cvtpk_bf16(p[2], p[3]);
    A.u[2] = cvtpk_bf16(p[4], p[5]);
    A.u[3] = cvtpk_bf16(p[6], p[7]);

    union { bf16x8 v; uint4 q; } B;
    uint4 ld = *(const uint4*)(bsrcJ + (size_t)(c*4 + kg)*64 + (col & 7)*8);  // contiguous 512B/wave
    B.q.x = bge8 ? 0x3f803f80u : ld.x;   // col>=8: bf16 1.0 (col 8 = denominator)
    B.q.y = bge8 ? 0x3f803f80u : ld.y;
    B.q.z = bge8 ? 0x3f803f80u : ld.z;
    B.q.w = bge8 ? 0x3f803f80u : ld.w;

    acc = __builtin_amdgcn_mfma_f32_16x16x32_bf16(A.v, B.v, acc, 0, 0, 0);
  }

  s_acc[js][lane] = acc;
  __syncthreads();
  if (js == 0){
    f32x4 a1 = s_acc[1][lane], a2 = s_acc[2][lane], a3 = s_acc[3][lane];
    #pragma unroll
    for (int j = 0; j < 4; ++j) acc[j] += a1[j] + a2[j] + a3[j];

    int slane = (lane & 48) + 8;
    #pragma unroll
    for (int r4 = 0; r4 < 4; ++r4){
      float sv = __shfl(acc[r4], slane, 64);
      float inv = 1.f / fmaxf(sv, 1e-10f);
      if (col < 8)
        posg[(size_t)(i0 + kg*4 + r4)*64 + h*8 + col] = acc[r4] * inv;
    }
  }
}

// ---------------- K4: residual proj + the two MLP channels + PairNorm partials ----------------
__global__ __launch_bounds__(256) void k4_mix(
    const float* __restrict__ h, const float* __restrict__ posg,
    const float* __restrict__ gat_bias, const float* __restrict__ proj_b,
    const float* __restrict__ wtproj, const float* __restrict__ wtself,
    const float* __restrict__ wtpos,
    const float* __restrict__ mlp_self_b, const float* __restrict__ mlp_pos_b,
    float* __restrict__ s0, float* __restrict__ s1, float* __restrict__ part)
{
  int tid = threadIdx.x;
  int wave = tid >> 6, lane = tid & 63;
  int n = blockIdx.x*4 + wave;
  float hreg = h[n*64 + lane];
  float pr = proj_b[lane];
  float se = mlp_self_b[lane];
  #pragma unroll
  for (int k = 0; k < 64; ++k){
    float hk = __shfl(hreg, k, 64);
    pr += hk * wtproj[k*64 + lane];
    se += hk * wtself[k*64 + lane];
  }
  float posf = posg[n*64 + lane] + gat_bias[lane] + pr;
  float s1v = mlp_pos_b[lane];
  #pragma unroll
  for (int k = 0; k < 64; ++k){
    float pk = __shfl(posf, k, 64);
    s1v += pk * wtpos[k*64 + lane];
  }
  s0[n*64+lane] = se;
  s1[n*64+lane] = s1v;

  __shared__ float sb0[4][64];
  __shared__ float sb1[4][64];
  __shared__ float sq[4];
  sb0[wave][lane] = se;
  sb1[wave][lane] = s1v;
  float q = se*se + s1v*s1v;
  #pragma unroll
  for (int s = 1; s < 64; s <<= 1) q += __shfl_xor(q, s, 64);
  if (lane == 0) sq[wave] = q;
  __syncthreads();
  if (tid < 64){
    part[blockIdx.x*130 + tid] = sb0[0][tid]+sb0[1][tid]+sb0[2][tid]+sb0[3][tid];
  } else if (tid < 128){
    int d = tid - 64;
    part[blockIdx.x*130 + 64 + d] = sb1[0][d]+sb1[1][d]+sb1[2][d]+sb1[3][d];
  } else if (tid == 128){
    part[blockIdx.x*130 + 128] = sq[0]+sq[1]+sq[2]+sq[3];
  }
}

// ---------------- K5: PairNorm stats (1024-thread two-stage reduce) ----------------
__global__ __launch_bounds__(1024) void k5_stats(const float* __restrict__ part, float* __restrict__ stats)
{
  int tid = threadIdx.x;
  __shared__ float s_mu[8][128];
  __shared__ float s_sq[8];
  int c = tid & 127, ch = tid >> 7;
  float a = 0.f;
  for (int b = ch*128; b < ch*128+128; ++b) a += part[b*130 + c];
  s_mu[ch][c] = a;
  if (tid < 8){
    float q = 0.f;
    for (int b = tid*128; b < tid*128+128; ++b) q += part[b*130 + 128];
    s_sq[tid] = q;
  }
  __syncthreads();
  if (tid < 128){
    float m = 0.f;
    #pragma unroll
    for (int j = 0; j < 8; ++j) m += s_mu[j][tid];
    s_mu[0][tid] = m;
    stats[tid] = m / 4096.f;
  }
  __syncthreads();
  if (tid == 0){
    float sq = 0.f;
    #pragma unroll
    for (int j = 0; j < 8; ++j) sq += s_sq[j];
    float mu2 = 0.f;
    for (int i = 0; i < 128; ++i){ float m = s_mu[0][i] / 4096.f; mu2 += m*m; }
    float msq = sq/(4096.f*64.f) - mu2/64.f;
    stats[128] = 1.f / sqrtf(1e-6f + msq);
  }
}

// ---------------- K6: semantic attention + predictor ----------------
__global__ __launch_bounds__(256) void k6_sem(
    const float* __restrict__ s0, const float* __restrict__ s1,
    const float* __restrict__ stats, const float* __restrict__ wtsem,
    const float* __restrict__ sem_b1, const float* __restrict__ sem_w2,
    const float* __restrict__ pred_w, const float* __restrict__ pred_b,
    float* __restrict__ out)
{
  int tid = threadIdx.x;
  int wave = tid >> 6, lane = tid & 63;
  int n = blockIdx.x*4 + wave;
  float rinv = stats[128];
  float a0 = (s0[n*64+lane] - stats[lane]) * rinv;
  float a1 = (s1[n*64+lane] - stats[64+lane]) * rinv;
  float t0 = sem_b1[lane], t1 = t0;
  #pragma unroll
  for (int k = 0; k < 64; ++k){
    float w = wtsem[k*64 + lane];
    t0 += __shfl(a0, k, 64) * w;
    t1 += __shfl(a1, k, 64) * w;
  }
  t0 = tanh_fast(t0); t1 = tanh_fast(t1);
  float w2 = sem_w2[lane];
  float w0 = t0*w2, w1 = t1*w2;
  #pragma unroll
  for (int s = 1; s < 64; s <<= 1){
    w0 += __shfl_xor(w0, s, 64);
    w1 += __shfl_xor(w1, s, 64);
  }
  float mx = fmaxf(w0, w1);
  float e0 = __expf(w0 - mx), e1 = __expf(w1 - mx);
  float denom = e0 + e1 + 1e-10f;
  float b0 = e0/denom, b1 = e1/denom;
  float emb = b0*a0 + b1*a1;
  float pl = emb * pred_w[lane];
  #pragma unroll
  for (int s = 1; s < 64; s <<= 1) pl += __shfl_xor(pl, s, 64);
  if (lane == 0) out[n] = sigm(pl + pred_b[0]);
}

extern "C" void kernel_launch(void* const* d_in, const int* in_sizes, int n_in,
                              void* d_out, int out_size, void* d_ws, size_t ws_size,
                              hipStream_t stream)
{
  (void)in_sizes; (void)n_in; (void)out_size; (void)ws_size;
  const float* x         = (const float*)d_in[0];
  const int*   adj       = (const int*)d_in[1];
  const float* W_ih      = (const float*)d_in[2];
  const float* W_hh      = (const float*)d_in[3];
  const float* b_ih      = (const float*)d_in[4];
  const float* b_hh      = (const float*)d_in[5];
  const float* gat_w     = (const float*)d_in[6];
  const float* gat_wu    = (const float*)d_in[7];
  const float* gat_wv    = (const float*)d_in[8];
  const float* gat_bias  = (const float*)d_in[9];
  const float* proj_w    = (const float*)d_in[10];
  const float* proj_b    = (const float*)d_in[11];
  const float* mlp_self_w= (const float*)d_in[12];
  const float* mlp_self_b= (const float*)d_in[13];
  const float* mlp_pos_w = (const float*)d_in[14];
  const float* mlp_pos_b = (const float*)d_in[15];
  const float* sem_w1    = (const float*)d_in[16];
  const float* sem_b1    = (const float*)d_in[17];
  const float* sem_w2    = (const float*)d_in[18];
  const float* pred_w    = (const float*)d_in[19];
  const float* pred_b    = (const float*)d_in[20];
  float* out = (float*)d_out;
  float* ws  = (float*)d_ws;

  float* h     = ws + 0;         // 0..262144
  unsigned short* supbJ = (unsigned short*)(ws + 262144);   // 512KB -> ends 393216
  float* f1t   = ws + 393216;    // 32768 -> 425984
  float* f2    = ws + 425984;    // 32768 -> 458752
  uint4* whhF  = (uint4*)(ws + 458752);   // 1536 uint4 = 6144 floats -> 464896
  uint4* wihF  = (uint4*)(ws + 464896);   // 768 uint4 = 3072 floats -> 467968
  float* posg  = ws + 589824;    // 262144 -> 851968
  float* s0    = ws + 851968;    // 262144
  float* s1    = ws + 1114112;   // 262144
  // adjmT overlays s0+s1 (2MB, 851968..1376256): written by k1_fused pack-blocks,
  // consumed by k3, dead before k4 writes s0/s1. whhF/wihF are OUTSIDE this range.
  unsigned long long* adjmT = (unsigned long long*)(ws + 851968);
  float* part  = ws + 1376256;   // 1024*130
  float* stats = ws + 1517576;   // 129
  float* wtproj= ws + 1517712;   // 4096
  float* wtself= wtproj + 4096;
  float* wtpos = wtself + 4096;
  float* wtsem = wtpos  + 4096;

  k0_prep<<<25, 256, 0, stream>>>(proj_w, mlp_self_w, mlp_pos_w, sem_w1,
                                  W_ih, W_hh, b_ih, b_hh,
                                  wtproj, wtself, wtpos, wtsem, whhF, wihF);
  k1_fused<<<1280, 256, 0, stream>>>(x, whhF, wihF, b_hh, h, adj, adjmT);
  k2_sup<<<1024, 256, 0, stream>>>(h, gat_w, gat_wu, gat_wv, supbJ, f1t, f2);
  k3_gat<<<2048, 256, 0, stream>>>(adjmT, supbJ, f1t, f2, posg);
  k4_mix<<<1024, 256, 0, stream>>>(h, posg, gat_bias, proj_b, wtproj, wtself, wtpos,
                                   mlp_self_b, mlp_pos_b, s0, s1, part);
  k5_stats<<<1, 1024, 0, stream>>>(part, stats);
  k6_sem<<<1024, 256, 0, stream>>>(s0, s1, stats, wtsem, sem_b1, sem_w2, pred_w, pred_b, out);
}